// Round 23
// baseline (134.005 us; speedup 1.0000x reference)
//
#include <hip/hip_runtime.h>

#define N_TOK 3136   // 56*56
#define WOUT 56
#define CH 512
#define HD 64
#define LOG2E 1.44269504088896340736f

typedef _Float16 h4 __attribute__((ext_vector_type(4)));
typedef _Float16 h8 __attribute__((ext_vector_type(8)));
typedef float f32x4 __attribute__((ext_vector_type(4)));
typedef float f32x16 __attribute__((ext_vector_type(16)));
typedef unsigned u32x2 __attribute__((ext_vector_type(2)));
typedef unsigned u32x4 __attribute__((ext_vector_type(4)));

// ws offsets in f16 elements
#define WS_XH 0                 // x f16 (3211264), dead after k_proj -> pO split 0
#define WS_WF 3211264           // w f16 (786432)
#define WS_QT 3997696
#define WS_KT 7208960
#define WS_VW 10420224
#define WS_PO13 13631488        // pO splits 1..3 (3 x 3211264)
#define WS_ML 23265280          // f32 m/l arrays
#define SPLIT_O 3211264         // per-split partial-O element count (16*64*3136)
#define ML_N 200704             // 4*16*3136 per array

__device__ inline unsigned pkh(float a, float b) {
    return __builtin_bit_cast(unsigned, __builtin_amdgcn_cvt_pkrtz(a, b));
}
// raw v_exp_f32: 2^x
__device__ inline float fexp2(float x) {
#if __has_builtin(__builtin_amdgcn_exp2f)
    return __builtin_amdgcn_exp2f(x);
#else
    float r;
    asm("v_exp_f32 %0, %1" : "=v"(r) : "v"(x));
    return r;
#endif
}
// raw v_log_f32: log2(x)
__device__ inline float flog2(float x) {
#if __has_builtin(__builtin_amdgcn_logf)
    return __builtin_amdgcn_logf(x);
#else
    float r;
    asm("v_log_f32 %0, %1" : "=v"(r) : "v"(x));
    return r;
#endif
}
// raw v_rcp_f32
__device__ inline float frcp(float x) {
#if __has_builtin(__builtin_amdgcn_rcpf)
    return __builtin_amdgcn_rcpf(x);
#else
    float r;
    asm("v_rcp_f32 %0, %1" : "=v"(r) : "v"(x));
    return r;
#endif
}
// swap: lanes>=32 of a  <->  lanes<32 of b
__device__ inline void plswap(unsigned& a, unsigned& b) {
#if __has_builtin(__builtin_amdgcn_permlane32_swap)
    u32x2 r = __builtin_amdgcn_permlane32_swap(a, b, false, false);
    a = r.x; b = r.y;
#else
    unsigned a2 = (unsigned)__shfl_xor((int)a, 32);
    unsigned b2 = (unsigned)__shfl_xor((int)b, 32);
    bool hi = (threadIdx.x & 63) >= 32;
    unsigned na = hi ? b2 : a;
    unsigned nb = hi ? b : a2;
    a = na; b = nb;
#endif
}

// ---------- downsample + transpose + f16; y==8 blocks convert w ----------
__global__ __launch_bounds__(256) void k_ds(const float* __restrict__ x,
                                            const float* __restrict__ w,
                                            _Float16* __restrict__ xh,
                                            _Float16* __restrict__ wf) {
    const int t = threadIdx.x;
    if (blockIdx.y == 8) {   // w fp32 -> f16 (1536*512 = 786432 elements)
        int base = (blockIdx.z * 49 + blockIdx.x) * 8192 + t;
        #pragma unroll 8
        for (int i = 0; i < 32; ++i) {
            int idx = base + i * 256;
            if (idx < 1536 * 512) wf[idx] = (_Float16)w[idx];
        }
        return;
    }
    __shared__ float tile[64 * 65];
    const int q = t >> 6, l = t & 63;
    const int n0 = blockIdx.x * 64, c0 = blockIdx.y * 64, b = blockIdx.z;
    #pragma unroll
    for (int r = 0; r < 16; ++r) {
        int c_l = q * 16 + r;
        int n = n0 + l;
        int hh = n / WOUT, ww = n - hh * WOUT;
        tile[c_l * 65 + l] =
            x[(((size_t)(b * CH + c0 + c_l)) * 112 + hh * 2) * 112 + ww * 2];
    }
    __syncthreads();
    #pragma unroll
    for (int r = 0; r < 16; ++r) {
        int n_l = q * 16 + r;
        xh[((size_t)b * N_TOK + n0 + n_l) * CH + c0 + l] = (_Float16)tile[l * 65 + n_l];
    }
}

// ---------- projection, 128x128 tile, BK=64; K pre-scaled by log2(e) ----------
__global__ __launch_bounds__(256) void k_proj(const _Float16* __restrict__ wf,
                                              const _Float16* __restrict__ xh,
                                              _Float16* __restrict__ qT,
                                              _Float16* __restrict__ kT,
                                              _Float16* __restrict__ vW) {
    __shared__ __align__(16) _Float16 Wt[128 * 72];
    __shared__ __align__(16) _Float16 Xt[128 * 72];
    const int t = threadIdx.x;
    const int mtn = blockIdx.x;                           // 0..24 token tiles
    const int n0 = (mtn == 24) ? (N_TOK - 128) : mtn * 128;  // benign overlap on last
    const int o0 = blockIdx.y * 128;
    const int b = blockIdx.z;
    const int w = t >> 6, L = t & 63, lm = L & 15, g = L >> 4;
    const int sr = t >> 1, sc = (t & 1) * 32;   // 128 rows x 2 col-chunks per thread

    f32x4 acc[2][8] = {};
    for (int kc = 0; kc < 8; ++kc) {
        const int c0 = kc * 64;
        const size_t wb = (size_t)(o0 + sr) * CH + c0 + sc;
        const size_t xb = ((size_t)b * N_TOK + n0 + sr) * CH + c0 + sc;
        h8 rw[4], rx[4];
        #pragma unroll
        for (int i = 0; i < 4; ++i) {
            rw[i] = *(const h8*)&wf[wb + i * 8];
            rx[i] = *(const h8*)&xh[xb + i * 8];
        }
        __syncthreads();   // previous iteration's reads done
        #pragma unroll
        for (int i = 0; i < 4; ++i) {
            *(h8*)&Wt[sr * 72 + sc + i * 8] = rw[i];
            *(h8*)&Xt[sr * 72 + sc + i * 8] = rx[i];
        }
        __syncthreads();
        #pragma unroll
        for (int kk2 = 0; kk2 < 2; ++kk2) {
            const int kb = kk2 * 32 + g * 8;
            h8 a0 = *(h8*)&Wt[(w * 32 + lm) * 72 + kb];
            h8 a1 = *(h8*)&Wt[(w * 32 + 16 + lm) * 72 + kb];
            #pragma unroll
            for (int nt = 0; nt < 8; ++nt) {
                h8 bf = *(h8*)&Xt[(nt * 16 + lm) * 72 + kb];
                acc[0][nt] = __builtin_amdgcn_mfma_f32_16x16x32_f16(a0, bf, acc[0][nt], 0, 0, 0);
                acc[1][nt] = __builtin_amdgcn_mfma_f32_16x16x32_f16(a1, bf, acc[1][nt], 0, 0, 0);
            }
        }
    }
    #pragma unroll
    for (int ot = 0; ot < 2; ++ot) {
        int obase = o0 + w * 32 + ot * 16;
        int h = obase / 192;
        int typ = (obase / 64) % 3;
        int dbase = obase & 63;
        #pragma unroll
        for (int nt = 0; nt < 8; ++nt) {
            int n = n0 + nt * 16 + lm;
            f32x4 a = acc[ot][nt];
            if (typ == 2) {
                #pragma unroll
                for (int j = 0; j < 4; ++j)
                    vW[((size_t)(b * 8 + h) * HD + dbase + g * 4 + j) * N_TOK + n] = (_Float16)a[j];
            } else if (typ == 1) {
                h4 hv = {(_Float16)(a[0] * LOG2E), (_Float16)(a[1] * LOG2E),
                         (_Float16)(a[2] * LOG2E), (_Float16)(a[3] * LOG2E)};
                *(h4*)&kT[((size_t)(b * 8 + h) * N_TOK + n) * HD + dbase + g * 4] = hv;
            } else {
                h4 hv = {(_Float16)a[0], (_Float16)a[1], (_Float16)a[2], (_Float16)a[3]};
                *(h4*)&qT[((size_t)(b * 8 + h) * N_TOK + n) * HD + dbase + g * 4] = hv;
            }
        }
    }
}

// ---------- flash attention: S=4, 4 waves share K/V tile, psum-guard (alpha-rescale) ----------
__global__ __launch_bounds__(256, 2) void k_attn(const _Float16* __restrict__ qT,
                                                 const _Float16* __restrict__ kT,
                                                 const _Float16* __restrict__ vW,
                                                 _Float16* __restrict__ wsbase,
                                                 float* __restrict__ pm,
                                                 float* __restrict__ pl) {
    __shared__ __align__(16) _Float16 Ks[64 * 72];   // [n][d], pitch 72 halves
    __shared__ __align__(16) _Float16 Vs[64 * 72];   // [d][n], pitch 72

    const int t = threadIdx.x;
    const int w = t >> 6, L = t & 63, lm = L & 31, hi = L >> 5;

    // bijective chunked XCD swizzle: 1600 blocks = 8 XCDs x 200
    const int lin = blockIdx.x + 25 * blockIdx.y + 400 * blockIdx.z;
    const int nl = (lin & 7) * 200 + (lin >> 3);
    const int combo = nl / 25;              // 0..63 : (split, bh)
    const int mt = nl - combo * 25;
    const int bh = combo & 15;
    const int split = combo >> 4;
    // QBLK=128; clamp last block (benign overlap)
    const int qbase = (mt == 24) ? (N_TOK - 128) : mt * 128;
    const int mw = qbase + w * 32;

    const int cs = split * 12 + (split > 0 ? 1 : 0);   // {0,13,25,37}
    const int ce = cs + (split == 0 ? 13 : 12);

    // hoist Q (B-operand): lane: query col = lm, k-slice = hi*8
    const size_t qb = ((size_t)bh * N_TOK + mw + lm) * HD;
    h8 qf[4];
    #pragma unroll
    for (int ks = 0; ks < 4; ++ks) qf[ks] = *(const h8*)&qT[qb + ks * 16 + hi * 8];

    const int sr = t >> 2;                  // staging row 0..63 (4 threads/row)
    const int scol = (t & 3) * 16;          // element offset within row (2 h8)
    const _Float16* ka = kT + (size_t)bh * N_TOK * HD + (size_t)(cs * 64 + sr) * HD + scol;
    const _Float16* va = vW + (size_t)bh * HD * N_TOK + (size_t)sr * N_TOK + cs * 64 + scol;

    float m_run = 0.f, l_run = 0.f;
    f32x16 o_acc[2] = {};

    // prologue: stage first chunk
    {
        h8 pk0 = *(const h8*)&ka[0], pk1 = *(const h8*)&ka[8];
        h8 pv0 = *(const h8*)&va[0], pv1 = *(const h8*)&va[8];
        ka += 64 * HD; va += 64;
        *(h8*)&Ks[sr * 72 + scol] = pk0; *(h8*)&Ks[sr * 72 + scol + 8] = pk1;
        *(h8*)&Vs[sr * 72 + scol] = pv0; *(h8*)&Vs[sr * 72 + scol + 8] = pv1;
    }
    __syncthreads();

    for (int ch = cs; ch < ce; ++ch) {
        const bool pf = (ch + 1 < ce);
        h8 pk0, pk1, pv0, pv1;
        if (pf) {   // issue next-chunk loads early; latency hides under compute
            pk0 = *(const h8*)&ka[0]; pk1 = *(const h8*)&ka[8];
            pv0 = *(const h8*)&va[0]; pv1 = *(const h8*)&va[8];
            ka += 64 * HD; va += 64;
        }

        // QK^T (swapped): A = K rows (keys), B = Q; D[key][query]; logits in log2 units
        f32x16 s0 = {}, s1 = {};
        __builtin_amdgcn_s_setprio(1);
        #pragma unroll
        for (int ks = 0; ks < 4; ++ks) {
            h8 a0 = *(const h8*)&Ks[lm * 72 + ks * 16 + hi * 8];
            h8 a1 = *(const h8*)&Ks[(32 + lm) * 72 + ks * 16 + hi * 8];
            s0 = __builtin_amdgcn_mfma_f32_32x32x16_f16(a0, qf[ks], s0, 0, 0, 0);
            s1 = __builtin_amdgcn_mfma_f32_32x32x16_f16(a1, qf[ks], s1, 0, 0, 0);
        }
        __builtin_amdgcn_s_setprio(0);

        // psum-guard softmax: exp with current shift (in place, s dies -> p)
        if (ch == cs) {   // peeled first chunk: establish m_run via full cmax
            float cmax = -1e30f;
            #pragma unroll
            for (int r = 0; r < 16; ++r) cmax = fmaxf(cmax, fmaxf(s0[r], s1[r]));
            cmax = fmaxf(cmax, __shfl_xor(cmax, 32));
            m_run = cmax;
        }
        float psum = 0.f;
        #pragma unroll
        for (int r = 0; r < 16; ++r) {
            s0[r] = fexp2(s0[r] - m_run);
            s1[r] = fexp2(s1[r] - m_run);
            psum += s0[r] + s1[r];
        }
        if (__any(psum > 4096.f)) {   // rare: chunk max jumped > ~12 log2-units
            float maxp = 0.f;
            #pragma unroll
            for (int r = 0; r < 16; ++r) maxp = fmaxf(maxp, fmaxf(s0[r], s1[r]));
            maxp = fmaxf(maxp, __shfl_xor(maxp, 32));
            float alpha = frcp(maxp);    // p_new = p * alpha <= 1
            m_run += flog2(maxp);
            l_run *= alpha;
            psum *= alpha;
            #pragma unroll
            for (int r = 0; r < 16; ++r) {
                o_acc[0][r] *= alpha; o_acc[1][r] *= alpha;
                s0[r] *= alpha;       s1[r] *= alpha;
            }
        }
        psum += __shfl_xor(psum, 32);
        l_run += psum;

        // P -> B-operand fragments in-register (cvt_pkrtz + permlane32_swap)
        h8 pfrag[4];
        #pragma unroll
        for (int kt = 0; kt < 2; ++kt) {
            #pragma unroll
            for (int half = 0; half < 2; ++half) {
                const int b0 = half * 8;
                const f32x16& pp = kt ? s1 : s0;
                unsigned w01 = pkh(pp[b0 + 0], pp[b0 + 1]);
                unsigned w23 = pkh(pp[b0 + 2], pp[b0 + 3]);
                unsigned w45 = pkh(pp[b0 + 4], pp[b0 + 5]);
                unsigned w67 = pkh(pp[b0 + 6], pp[b0 + 7]);
                plswap(w01, w45);
                plswap(w23, w67);
                u32x4 uu = {w01, w23, w45, w67};
                pfrag[kt * 2 + half] = __builtin_bit_cast(h8, uu);
            }
        }

        // PV: A = V rows (d), B = P; D[d][query]
        __builtin_amdgcn_s_setprio(1);
        #pragma unroll
        for (int ns = 0; ns < 4; ++ns) {
            h8 av0 = *(const h8*)&Vs[lm * 72 + ns * 16 + hi * 8];
            h8 av1 = *(const h8*)&Vs[(32 + lm) * 72 + ns * 16 + hi * 8];
            o_acc[0] = __builtin_amdgcn_mfma_f32_32x32x16_f16(av0, pfrag[ns], o_acc[0], 0, 0, 0);
            o_acc[1] = __builtin_amdgcn_mfma_f32_32x32x16_f16(av1, pfrag[ns], o_acc[1], 0, 0, 0);
        }
        __builtin_amdgcn_s_setprio(0);

        if (pf) {
            __syncthreads();   // all waves done reading Ks/Vs
            *(h8*)&Ks[sr * 72 + scol] = pk0; *(h8*)&Ks[sr * 72 + scol + 8] = pk1;
            *(h8*)&Vs[sr * 72 + scol] = pv0; *(h8*)&Vs[sr * 72 + scol + 8] = pv1;
            __syncthreads();   // new tile visible
        }
    }

    // epilogue: store per-split normalized O (f16) + m,l (f32)
    float inv = 1.0f / l_run;
    _Float16* pO = (split == 0) ? wsbase
                                : wsbase + WS_PO13 + (size_t)(split - 1) * SPLIT_O;
    const size_t pob = (size_t)bh * HD * N_TOK + mw + lm;
    #pragma unroll
    for (int dt = 0; dt < 2; ++dt)
        #pragma unroll
        for (int r = 0; r < 16; ++r) {
            int d = dt * 32 + (r & 3) + 8 * (r >> 2) + 4 * hi;
            pO[pob + (size_t)d * N_TOK] = (_Float16)(o_acc[dt][r] * inv);
        }
    if (hi == 0) {
        pm[(split * 16 + bh) * N_TOK + mw + lm] = m_run;
        pl[(split * 16 + bh) * N_TOK + mw + lm] = l_run;
    }
}

// ---------- combine the four key-splits (exact online-softmax merge) ----------
__global__ __launch_bounds__(256) void k_comb(const _Float16* __restrict__ wsbase,
                                              const float* __restrict__ pm,
                                              const float* __restrict__ pl,
                                              float* __restrict__ out) {
    int idx = blockIdx.x * 256 + threadIdx.x;   // 16*64*3136 = 12544*256 exactly
    int n = idx % N_TOK;
    int bh = (idx / N_TOK) >> 6;
    float m[4], l[4];
    #pragma unroll
    for (int s = 0; s < 4; ++s) {
        m[s] = pm[(s * 16 + bh) * N_TOK + n];
        l[s] = pl[(s * 16 + bh) * N_TOK + n];
    }
    float mm = fmaxf(fmaxf(m[0], m[1]), fmaxf(m[2], m[3]));
    float num = 0.f, den = 0.f;
    #pragma unroll
    for (int s = 0; s < 4; ++s) {
        const _Float16* pO = (s == 0) ? wsbase
                                      : wsbase + WS_PO13 + (size_t)(s - 1) * SPLIT_O;
        float wg = fexp2(m[s] - mm) * l[s];
        num += (float)pO[idx] * wg;
        den += wg;
    }
    out[idx] = num / den;
}

extern "C" void kernel_launch(void* const* d_in, const int* in_sizes, int n_in,
                              void* d_out, int out_size, void* d_ws, size_t ws_size,
                              hipStream_t stream) {
    const float* x = (const float*)d_in[0];
    const float* wq = (const float*)d_in[1];
    float* out = (float*)d_out;
    _Float16* ws = (_Float16*)d_ws;

    _Float16* xh = ws + WS_XH;
    _Float16* wf = ws + WS_WF;
    _Float16* qT = ws + WS_QT;
    _Float16* kT = ws + WS_KT;
    _Float16* vW = ws + WS_VW;
    float* pm = (float*)(ws + WS_ML);
    float* pl = pm + ML_N;

    k_ds<<<dim3(49, 9, 2), 256, 0, stream>>>(x, wq, xh, wf);
    k_proj<<<dim3(25, 12, 2), 256, 0, stream>>>(wf, xh, qT, kT, vW);
    k_attn<<<dim3(25, 16, 4), 256, 0, stream>>>(qT, kT, vW, ws, pm, pl);
    k_comb<<<dim3(12544), 256, 0, stream>>>(ws, pm, pl, out);
}

// Round 24
// 128.369 us; speedup vs baseline: 1.0439x; 1.0439x over previous
//
#include <hip/hip_runtime.h>

#define N_TOK 3136   // 56*56
#define WOUT 56
#define CH 512
#define HD 64
#define LOG2E 1.44269504088896340736f

typedef _Float16 h4 __attribute__((ext_vector_type(4)));
typedef _Float16 h8 __attribute__((ext_vector_type(8)));
typedef float f32x4 __attribute__((ext_vector_type(4)));
typedef float f32x16 __attribute__((ext_vector_type(16)));
typedef unsigned u32x2 __attribute__((ext_vector_type(2)));
typedef unsigned u32x4 __attribute__((ext_vector_type(4)));

// ws offsets in f16 elements
#define WS_XH 0                 // x f16 (3211264), dead after k_proj -> pO split 0
#define WS_WF 3211264           // w f16 (786432)
#define WS_QT 3997696
#define WS_KT 7208960
#define WS_VW 10420224
#define WS_PO13 13631488        // pO splits 1..3 (3 x 3211264)
#define WS_ML 23265280          // f32 m/l arrays
#define SPLIT_O 3211264         // per-split partial-O element count (16*64*3136)
#define ML_N 200704             // 4*16*3136 per array

__device__ inline unsigned pkh(float a, float b) {
    return __builtin_bit_cast(unsigned, __builtin_amdgcn_cvt_pkrtz(a, b));
}
// raw v_exp_f32: 2^x, single instruction (avoid precise-libm exp2f)
__device__ inline float fexp2(float x) {
#if __has_builtin(__builtin_amdgcn_exp2f)
    return __builtin_amdgcn_exp2f(x);
#else
    float r;
    asm("v_exp_f32 %0, %1" : "=v"(r) : "v"(x));
    return r;
#endif
}
// swap: lanes>=32 of a  <->  lanes<32 of b
__device__ inline void plswap(unsigned& a, unsigned& b) {
#if __has_builtin(__builtin_amdgcn_permlane32_swap)
    u32x2 r = __builtin_amdgcn_permlane32_swap(a, b, false, false);
    a = r.x; b = r.y;
#else
    unsigned a2 = (unsigned)__shfl_xor((int)a, 32);
    unsigned b2 = (unsigned)__shfl_xor((int)b, 32);
    bool hi = (threadIdx.x & 63) >= 32;
    unsigned na = hi ? b2 : a;
    unsigned nb = hi ? b : a2;
    a = na; b = nb;
#endif
}

// ---------- downsample + transpose + f16; y==8 blocks convert w ----------
__global__ __launch_bounds__(256) void k_ds(const float* __restrict__ x,
                                            const float* __restrict__ w,
                                            _Float16* __restrict__ xh,
                                            _Float16* __restrict__ wf) {
    const int t = threadIdx.x;
    if (blockIdx.y == 8) {   // w fp32 -> f16 (1536*512 = 786432 elements)
        int base = (blockIdx.z * 49 + blockIdx.x) * 8192 + t;
        #pragma unroll 8
        for (int i = 0; i < 32; ++i) {
            int idx = base + i * 256;
            if (idx < 1536 * 512) wf[idx] = (_Float16)w[idx];
        }
        return;
    }
    __shared__ float tile[64 * 65];
    const int q = t >> 6, l = t & 63;
    const int n0 = blockIdx.x * 64, c0 = blockIdx.y * 64, b = blockIdx.z;
    #pragma unroll
    for (int r = 0; r < 16; ++r) {
        int c_l = q * 16 + r;
        int n = n0 + l;
        int hh = n / WOUT, ww = n - hh * WOUT;
        tile[c_l * 65 + l] =
            x[(((size_t)(b * CH + c0 + c_l)) * 112 + hh * 2) * 112 + ww * 2];
    }
    __syncthreads();
    #pragma unroll
    for (int r = 0; r < 16; ++r) {
        int n_l = q * 16 + r;
        xh[((size_t)b * N_TOK + n0 + n_l) * CH + c0 + l] = (_Float16)tile[l * 65 + n_l];
    }
}

// ---------- projection, 128x128 tile, BK=64; K pre-scaled by log2(e) ----------
__global__ __launch_bounds__(256) void k_proj(const _Float16* __restrict__ wf,
                                              const _Float16* __restrict__ xh,
                                              _Float16* __restrict__ qT,
                                              _Float16* __restrict__ kT,
                                              _Float16* __restrict__ vW) {
    __shared__ __align__(16) _Float16 Wt[128 * 72];
    __shared__ __align__(16) _Float16 Xt[128 * 72];
    const int t = threadIdx.x;
    const int mtn = blockIdx.x;                           // 0..24 token tiles
    const int n0 = (mtn == 24) ? (N_TOK - 128) : mtn * 128;  // benign overlap on last
    const int o0 = blockIdx.y * 128;
    const int b = blockIdx.z;
    const int w = t >> 6, L = t & 63, lm = L & 15, g = L >> 4;
    const int sr = t >> 1, sc = (t & 1) * 32;   // 128 rows x 2 col-chunks per thread

    f32x4 acc[2][8] = {};
    for (int kc = 0; kc < 8; ++kc) {
        const int c0 = kc * 64;
        const size_t wb = (size_t)(o0 + sr) * CH + c0 + sc;
        const size_t xb = ((size_t)b * N_TOK + n0 + sr) * CH + c0 + sc;
        h8 rw[4], rx[4];
        #pragma unroll
        for (int i = 0; i < 4; ++i) {
            rw[i] = *(const h8*)&wf[wb + i * 8];
            rx[i] = *(const h8*)&xh[xb + i * 8];
        }
        __syncthreads();   // previous iteration's reads done
        #pragma unroll
        for (int i = 0; i < 4; ++i) {
            *(h8*)&Wt[sr * 72 + sc + i * 8] = rw[i];
            *(h8*)&Xt[sr * 72 + sc + i * 8] = rx[i];
        }
        __syncthreads();
        #pragma unroll
        for (int kk2 = 0; kk2 < 2; ++kk2) {
            const int kb = kk2 * 32 + g * 8;
            h8 a0 = *(h8*)&Wt[(w * 32 + lm) * 72 + kb];
            h8 a1 = *(h8*)&Wt[(w * 32 + 16 + lm) * 72 + kb];
            #pragma unroll
            for (int nt = 0; nt < 8; ++nt) {
                h8 bf = *(h8*)&Xt[(nt * 16 + lm) * 72 + kb];
                acc[0][nt] = __builtin_amdgcn_mfma_f32_16x16x32_f16(a0, bf, acc[0][nt], 0, 0, 0);
                acc[1][nt] = __builtin_amdgcn_mfma_f32_16x16x32_f16(a1, bf, acc[1][nt], 0, 0, 0);
            }
        }
    }
    #pragma unroll
    for (int ot = 0; ot < 2; ++ot) {
        int obase = o0 + w * 32 + ot * 16;
        int h = obase / 192;
        int typ = (obase / 64) % 3;
        int dbase = obase & 63;
        #pragma unroll
        for (int nt = 0; nt < 8; ++nt) {
            int n = n0 + nt * 16 + lm;
            f32x4 a = acc[ot][nt];
            if (typ == 2) {
                #pragma unroll
                for (int j = 0; j < 4; ++j)
                    vW[((size_t)(b * 8 + h) * HD + dbase + g * 4 + j) * N_TOK + n] = (_Float16)a[j];
            } else if (typ == 1) {
                h4 hv = {(_Float16)(a[0] * LOG2E), (_Float16)(a[1] * LOG2E),
                         (_Float16)(a[2] * LOG2E), (_Float16)(a[3] * LOG2E)};
                *(h4*)&kT[((size_t)(b * 8 + h) * N_TOK + n) * HD + dbase + g * 4] = hv;
            } else {
                h4 hv = {(_Float16)a[0], (_Float16)a[1], (_Float16)a[2], (_Float16)a[3]};
                *(h4*)&qT[((size_t)(b * 8 + h) * N_TOK + n) * HD + dbase + g * 4] = hv;
            }
        }
    }
}

// ---------- flash attention: S=4, 4 waves share K/V tile, defer-max softmax (R22) ----------
__global__ __launch_bounds__(256, 2) void k_attn(const _Float16* __restrict__ qT,
                                                 const _Float16* __restrict__ kT,
                                                 const _Float16* __restrict__ vW,
                                                 _Float16* __restrict__ wsbase,
                                                 float* __restrict__ pm,
                                                 float* __restrict__ pl) {
    __shared__ __align__(16) _Float16 Ks[64 * 72];   // [n][d], pitch 72 halves
    __shared__ __align__(16) _Float16 Vs[64 * 72];   // [d][n], pitch 72

    const int t = threadIdx.x;
    const int w = t >> 6, L = t & 63, lm = L & 31, hi = L >> 5;

    // bijective chunked XCD swizzle: 1600 blocks = 8 XCDs x 200
    const int lin = blockIdx.x + 25 * blockIdx.y + 400 * blockIdx.z;
    const int nl = (lin & 7) * 200 + (lin >> 3);
    const int combo = nl / 25;              // 0..63 : (split, bh)
    const int mt = nl - combo * 25;
    const int bh = combo & 15;
    const int split = combo >> 4;
    // QBLK=128; clamp last block (benign overlap)
    const int qbase = (mt == 24) ? (N_TOK - 128) : mt * 128;
    const int mw = qbase + w * 32;

    const int cs = split * 12 + (split > 0 ? 1 : 0);   // {0,13,25,37}
    const int ce = cs + (split == 0 ? 13 : 12);

    // hoist Q (B-operand): lane: query col = lm, k-slice = hi*8
    const size_t qb = ((size_t)bh * N_TOK + mw + lm) * HD;
    h8 qf[4];
    #pragma unroll
    for (int ks = 0; ks < 4; ++ks) qf[ks] = *(const h8*)&qT[qb + ks * 16 + hi * 8];

    const int sr = t >> 2;                  // staging row 0..63 (4 threads/row)
    const int scol = (t & 3) * 16;          // element offset within row (2 h8)
    const _Float16* ka = kT + (size_t)bh * N_TOK * HD + (size_t)(cs * 64 + sr) * HD + scol;
    const _Float16* va = vW + (size_t)bh * HD * N_TOK + (size_t)sr * N_TOK + cs * 64 + scol;

    float m_run = -1e30f, l_run = 0.f;
    f32x16 o_acc[2] = {};

    // prologue: stage first chunk
    {
        h8 pk0 = *(const h8*)&ka[0], pk1 = *(const h8*)&ka[8];
        h8 pv0 = *(const h8*)&va[0], pv1 = *(const h8*)&va[8];
        ka += 64 * HD; va += 64;
        *(h8*)&Ks[sr * 72 + scol] = pk0; *(h8*)&Ks[sr * 72 + scol + 8] = pk1;
        *(h8*)&Vs[sr * 72 + scol] = pv0; *(h8*)&Vs[sr * 72 + scol + 8] = pv1;
    }
    __syncthreads();

    for (int ch = cs; ch < ce; ++ch) {
        const bool pf = (ch + 1 < ce);
        h8 pk0, pk1, pv0, pv1;
        if (pf) {   // issue next-chunk loads early; latency hides under compute
            pk0 = *(const h8*)&ka[0]; pk1 = *(const h8*)&ka[8];
            pv0 = *(const h8*)&va[0]; pv1 = *(const h8*)&va[8];
            ka += 64 * HD; va += 64;
        }

        // QK^T (swapped): A = K rows (keys), B = Q; D[key][query]; logits in log2 units
        f32x16 s0 = {}, s1 = {};
        __builtin_amdgcn_s_setprio(1);
        #pragma unroll
        for (int ks = 0; ks < 4; ++ks) {
            h8 a0 = *(const h8*)&Ks[lm * 72 + ks * 16 + hi * 8];
            h8 a1 = *(const h8*)&Ks[(32 + lm) * 72 + ks * 16 + hi * 8];
            s0 = __builtin_amdgcn_mfma_f32_32x32x16_f16(a0, qf[ks], s0, 0, 0, 0);
            s1 = __builtin_amdgcn_mfma_f32_32x32x16_f16(a1, qf[ks], s1, 0, 0, 0);
        }
        __builtin_amdgcn_s_setprio(0);

        // online softmax (exp2 space, raw v_exp_f32) with defer-max (THR=7)
        float cmax = -1e30f;
        #pragma unroll
        for (int r = 0; r < 16; ++r) cmax = fmaxf(cmax, fmaxf(s0[r], s1[r]));
        cmax = fmaxf(cmax, __shfl_xor(cmax, 32));
        if (!__all(cmax - m_run <= 7.f)) {
            float mnew = fmaxf(m_run, cmax);
            float alpha = fexp2(m_run - mnew);
            m_run = mnew;
            l_run *= alpha;
            #pragma unroll
            for (int r = 0; r < 16; ++r) { o_acc[0][r] *= alpha; o_acc[1][r] *= alpha; }
        }
        float p[2][16];
        float psum = 0.f;
        #pragma unroll
        for (int r = 0; r < 16; ++r) {
            p[0][r] = fexp2(s0[r] - m_run);
            p[1][r] = fexp2(s1[r] - m_run);
            psum += p[0][r] + p[1][r];
        }
        psum += __shfl_xor(psum, 32);
        l_run += psum;

        // P -> B-operand fragments in-register (cvt_pkrtz + permlane32_swap)
        h8 pfrag[4];
        #pragma unroll
        for (int kt = 0; kt < 2; ++kt) {
            #pragma unroll
            for (int half = 0; half < 2; ++half) {
                const int b0 = half * 8;
                unsigned w01 = pkh(p[kt][b0 + 0], p[kt][b0 + 1]);
                unsigned w23 = pkh(p[kt][b0 + 2], p[kt][b0 + 3]);
                unsigned w45 = pkh(p[kt][b0 + 4], p[kt][b0 + 5]);
                unsigned w67 = pkh(p[kt][b0 + 6], p[kt][b0 + 7]);
                plswap(w01, w45);
                plswap(w23, w67);
                u32x4 uu = {w01, w23, w45, w67};
                pfrag[kt * 2 + half] = __builtin_bit_cast(h8, uu);
            }
        }

        // PV: A = V rows (d), B = P; D[d][query]
        __builtin_amdgcn_s_setprio(1);
        #pragma unroll
        for (int ns = 0; ns < 4; ++ns) {
            h8 av0 = *(const h8*)&Vs[lm * 72 + ns * 16 + hi * 8];
            h8 av1 = *(const h8*)&Vs[(32 + lm) * 72 + ns * 16 + hi * 8];
            o_acc[0] = __builtin_amdgcn_mfma_f32_32x32x16_f16(av0, pfrag[ns], o_acc[0], 0, 0, 0);
            o_acc[1] = __builtin_amdgcn_mfma_f32_32x32x16_f16(av1, pfrag[ns], o_acc[1], 0, 0, 0);
        }
        __builtin_amdgcn_s_setprio(0);

        if (pf) {
            __syncthreads();   // all waves done reading Ks/Vs
            *(h8*)&Ks[sr * 72 + scol] = pk0; *(h8*)&Ks[sr * 72 + scol + 8] = pk1;
            *(h8*)&Vs[sr * 72 + scol] = pv0; *(h8*)&Vs[sr * 72 + scol + 8] = pv1;
            __syncthreads();   // new tile visible
        }
    }

    // epilogue: store per-split normalized O (f16) + m,l (f32)
    float inv = 1.0f / l_run;
    _Float16* pO = (split == 0) ? wsbase
                                : wsbase + WS_PO13 + (size_t)(split - 1) * SPLIT_O;
    const size_t pob = (size_t)bh * HD * N_TOK + mw + lm;
    #pragma unroll
    for (int dt = 0; dt < 2; ++dt)
        #pragma unroll
        for (int r = 0; r < 16; ++r) {
            int d = dt * 32 + (r & 3) + 8 * (r >> 2) + 4 * hi;
            pO[pob + (size_t)d * N_TOK] = (_Float16)(o_acc[dt][r] * inv);
        }
    if (hi == 0) {
        pm[(split * 16 + bh) * N_TOK + mw + lm] = m_run;
        pl[(split * 16 + bh) * N_TOK + mw + lm] = l_run;
    }
}

// ---------- combine the four key-splits, 4 elements/thread (vectorized) ----------
__global__ __launch_bounds__(256) void k_comb(const _Float16* __restrict__ wsbase,
                                              const float* __restrict__ pm,
                                              const float* __restrict__ pl,
                                              float* __restrict__ out) {
    // 3,211,264 elements = 3136 blocks x 256 threads x 4
    int base = (blockIdx.x * 256 + threadIdx.x) * 4;
    int n = base % N_TOK;                 // N_TOK % 4 == 0: packs never straddle rows
    int bh = (base / N_TOK) >> 6;
    f32x4 num = {}, den = {};
    float mm[4];
    f32x4 mv[4], lv[4];
    #pragma unroll
    for (int s = 0; s < 4; ++s) {
        mv[s] = *(const f32x4*)&pm[(s * 16 + bh) * N_TOK + n];
        lv[s] = *(const f32x4*)&pl[(s * 16 + bh) * N_TOK + n];
    }
    #pragma unroll
    for (int j = 0; j < 4; ++j)
        mm[j] = fmaxf(fmaxf(mv[0][j], mv[1][j]), fmaxf(mv[2][j], mv[3][j]));
    #pragma unroll
    for (int s = 0; s < 4; ++s) {
        const _Float16* pO = (s == 0) ? wsbase
                                      : wsbase + WS_PO13 + (size_t)(s - 1) * SPLIT_O;
        h4 ov = *(const h4*)&pO[base];
        #pragma unroll
        for (int j = 0; j < 4; ++j) {
            float wg = fexp2(mv[s][j] - mm[j]) * lv[s][j];
            num[j] += (float)ov[j] * wg;
            den[j] += wg;
        }
    }
    f32x4 res;
    #pragma unroll
    for (int j = 0; j < 4; ++j) res[j] = num[j] / den[j];
    *(f32x4*)&out[base] = res;
}

extern "C" void kernel_launch(void* const* d_in, const int* in_sizes, int n_in,
                              void* d_out, int out_size, void* d_ws, size_t ws_size,
                              hipStream_t stream) {
    const float* x = (const float*)d_in[0];
    const float* wq = (const float*)d_in[1];
    float* out = (float*)d_out;
    _Float16* ws = (_Float16*)d_ws;

    _Float16* xh = ws + WS_XH;
    _Float16* wf = ws + WS_WF;
    _Float16* qT = ws + WS_QT;
    _Float16* kT = ws + WS_KT;
    _Float16* vW = ws + WS_VW;
    float* pm = (float*)(ws + WS_ML);
    float* pl = pm + ML_N;

    k_ds<<<dim3(49, 9, 2), 256, 0, stream>>>(x, wq, xh, wf);
    k_proj<<<dim3(25, 12, 2), 256, 0, stream>>>(wf, xh, qT, kT, vW);
    k_attn<<<dim3(25, 16, 4), 256, 0, stream>>>(qT, kT, vW, ws, pm, pl);
    k_comb<<<dim3(3136), 256, 0, stream>>>(ws, pm, pl, out);
}

// Round 25
// 127.320 us; speedup vs baseline: 1.0525x; 1.0082x over previous
//
#include <hip/hip_runtime.h>

#define N_TOK 3136   // 56*56
#define WOUT 56
#define CH 512
#define HD 64
#define LOG2E 1.44269504088896340736f
#define KBUF 4608    // 64*72 halves per K/V buffer

typedef _Float16 h4 __attribute__((ext_vector_type(4)));
typedef _Float16 h8 __attribute__((ext_vector_type(8)));
typedef float f32x4 __attribute__((ext_vector_type(4)));
typedef float f32x16 __attribute__((ext_vector_type(16)));
typedef unsigned u32x2 __attribute__((ext_vector_type(2)));
typedef unsigned u32x4 __attribute__((ext_vector_type(4)));

// ws offsets in f16 elements
#define WS_XH 0                 // x f16 (3211264), dead after k_proj -> pO split 0
#define WS_WF 3211264           // w f16 (786432)
#define WS_QT 3997696
#define WS_KT 7208960
#define WS_VW 10420224
#define WS_PO13 13631488        // pO splits 1..3 (3 x 3211264)
#define WS_ML 23265280          // f32 m/l arrays
#define SPLIT_O 3211264         // per-split partial-O element count (16*64*3136)
#define ML_N 200704             // 4*16*3136 per array

__device__ inline unsigned pkh(float a, float b) {
    return __builtin_bit_cast(unsigned, __builtin_amdgcn_cvt_pkrtz(a, b));
}
// raw v_exp_f32: 2^x, single instruction (avoid precise-libm exp2f)
__device__ inline float fexp2(float x) {
#if __has_builtin(__builtin_amdgcn_exp2f)
    return __builtin_amdgcn_exp2f(x);
#else
    float r;
    asm("v_exp_f32 %0, %1" : "=v"(r) : "v"(x));
    return r;
#endif
}
// swap: lanes>=32 of a  <->  lanes<32 of b
__device__ inline void plswap(unsigned& a, unsigned& b) {
#if __has_builtin(__builtin_amdgcn_permlane32_swap)
    u32x2 r = __builtin_amdgcn_permlane32_swap(a, b, false, false);
    a = r.x; b = r.y;
#else
    unsigned a2 = (unsigned)__shfl_xor((int)a, 32);
    unsigned b2 = (unsigned)__shfl_xor((int)b, 32);
    bool hi = (threadIdx.x & 63) >= 32;
    unsigned na = hi ? b2 : a;
    unsigned nb = hi ? b : a2;
    a = na; b = nb;
#endif
}

// ---------- downsample + transpose + f16; y==8 blocks convert w ----------
__global__ __launch_bounds__(256) void k_ds(const float* __restrict__ x,
                                            const float* __restrict__ w,
                                            _Float16* __restrict__ xh,
                                            _Float16* __restrict__ wf) {
    const int t = threadIdx.x;
    if (blockIdx.y == 8) {   // w fp32 -> f16 (1536*512 = 786432 elements)
        int base = (blockIdx.z * 49 + blockIdx.x) * 8192 + t;
        #pragma unroll 8
        for (int i = 0; i < 32; ++i) {
            int idx = base + i * 256;
            if (idx < 1536 * 512) wf[idx] = (_Float16)w[idx];
        }
        return;
    }
    __shared__ float tile[64 * 65];
    const int q = t >> 6, l = t & 63;
    const int n0 = blockIdx.x * 64, c0 = blockIdx.y * 64, b = blockIdx.z;
    #pragma unroll
    for (int r = 0; r < 16; ++r) {
        int c_l = q * 16 + r;
        int n = n0 + l;
        int hh = n / WOUT, ww = n - hh * WOUT;
        tile[c_l * 65 + l] =
            x[(((size_t)(b * CH + c0 + c_l)) * 112 + hh * 2) * 112 + ww * 2];
    }
    __syncthreads();
    #pragma unroll
    for (int r = 0; r < 16; ++r) {
        int n_l = q * 16 + r;
        xh[((size_t)b * N_TOK + n0 + n_l) * CH + c0 + l] = (_Float16)tile[l * 65 + n_l];
    }
}

// ---------- projection, 128x128 tile, BK=64; K pre-scaled by log2(e) ----------
__global__ __launch_bounds__(256) void k_proj(const _Float16* __restrict__ wf,
                                              const _Float16* __restrict__ xh,
                                              _Float16* __restrict__ qT,
                                              _Float16* __restrict__ kT,
                                              _Float16* __restrict__ vW) {
    __shared__ __align__(16) _Float16 Wt[128 * 72];
    __shared__ __align__(16) _Float16 Xt[128 * 72];
    const int t = threadIdx.x;
    const int mtn = blockIdx.x;                           // 0..24 token tiles
    const int n0 = (mtn == 24) ? (N_TOK - 128) : mtn * 128;  // benign overlap on last
    const int o0 = blockIdx.y * 128;
    const int b = blockIdx.z;
    const int w = t >> 6, L = t & 63, lm = L & 15, g = L >> 4;
    const int sr = t >> 1, sc = (t & 1) * 32;   // 128 rows x 2 col-chunks per thread

    f32x4 acc[2][8] = {};
    for (int kc = 0; kc < 8; ++kc) {
        const int c0 = kc * 64;
        const size_t wb = (size_t)(o0 + sr) * CH + c0 + sc;
        const size_t xb = ((size_t)b * N_TOK + n0 + sr) * CH + c0 + sc;
        h8 rw[4], rx[4];
        #pragma unroll
        for (int i = 0; i < 4; ++i) {
            rw[i] = *(const h8*)&wf[wb + i * 8];
            rx[i] = *(const h8*)&xh[xb + i * 8];
        }
        __syncthreads();   // previous iteration's reads done
        #pragma unroll
        for (int i = 0; i < 4; ++i) {
            *(h8*)&Wt[sr * 72 + sc + i * 8] = rw[i];
            *(h8*)&Xt[sr * 72 + sc + i * 8] = rx[i];
        }
        __syncthreads();
        #pragma unroll
        for (int kk2 = 0; kk2 < 2; ++kk2) {
            const int kb = kk2 * 32 + g * 8;
            h8 a0 = *(h8*)&Wt[(w * 32 + lm) * 72 + kb];
            h8 a1 = *(h8*)&Wt[(w * 32 + 16 + lm) * 72 + kb];
            #pragma unroll
            for (int nt = 0; nt < 8; ++nt) {
                h8 bf = *(h8*)&Xt[(nt * 16 + lm) * 72 + kb];
                acc[0][nt] = __builtin_amdgcn_mfma_f32_16x16x32_f16(a0, bf, acc[0][nt], 0, 0, 0);
                acc[1][nt] = __builtin_amdgcn_mfma_f32_16x16x32_f16(a1, bf, acc[1][nt], 0, 0, 0);
            }
        }
    }
    #pragma unroll
    for (int ot = 0; ot < 2; ++ot) {
        int obase = o0 + w * 32 + ot * 16;
        int h = obase / 192;
        int typ = (obase / 64) % 3;
        int dbase = obase & 63;
        #pragma unroll
        for (int nt = 0; nt < 8; ++nt) {
            int n = n0 + nt * 16 + lm;
            f32x4 a = acc[ot][nt];
            if (typ == 2) {
                #pragma unroll
                for (int j = 0; j < 4; ++j)
                    vW[((size_t)(b * 8 + h) * HD + dbase + g * 4 + j) * N_TOK + n] = (_Float16)a[j];
            } else if (typ == 1) {
                h4 hv = {(_Float16)(a[0] * LOG2E), (_Float16)(a[1] * LOG2E),
                         (_Float16)(a[2] * LOG2E), (_Float16)(a[3] * LOG2E)};
                *(h4*)&kT[((size_t)(b * 8 + h) * N_TOK + n) * HD + dbase + g * 4] = hv;
            } else {
                h4 hv = {(_Float16)a[0], (_Float16)a[1], (_Float16)a[2], (_Float16)a[3]};
                *(h4*)&qT[((size_t)(b * 8 + h) * N_TOK + n) * HD + dbase + g * 4] = hv;
            }
        }
    }
}

// ---------- flash attention: S=4, 4 waves share K/V, double-buffer, 1 barrier/chunk ----------
__global__ __launch_bounds__(256, 2) void k_attn(const _Float16* __restrict__ qT,
                                                 const _Float16* __restrict__ kT,
                                                 const _Float16* __restrict__ vW,
                                                 _Float16* __restrict__ wsbase,
                                                 float* __restrict__ pm,
                                                 float* __restrict__ pl) {
    __shared__ __align__(16) _Float16 Ks[2 * KBUF];   // [buf][n][d], pitch 72
    __shared__ __align__(16) _Float16 Vs[2 * KBUF];   // [buf][d][n], pitch 72

    const int t = threadIdx.x;
    const int w = t >> 6, L = t & 63, lm = L & 31, hi = L >> 5;

    // bijective chunked XCD swizzle: 1600 blocks = 8 XCDs x 200
    const int lin = blockIdx.x + 25 * blockIdx.y + 400 * blockIdx.z;
    const int nl = (lin & 7) * 200 + (lin >> 3);
    const int combo = nl / 25;              // 0..63 : (split, bh)
    const int mt = nl - combo * 25;
    const int bh = combo & 15;
    const int split = combo >> 4;
    // QBLK=128; clamp last block (benign overlap)
    const int qbase = (mt == 24) ? (N_TOK - 128) : mt * 128;
    const int mw = qbase + w * 32;

    const int cs = split * 12 + (split > 0 ? 1 : 0);   // {0,13,25,37}
    const int ce = cs + (split == 0 ? 13 : 12);

    // hoist Q (B-operand): lane: query col = lm, k-slice = hi*8
    const size_t qb = ((size_t)bh * N_TOK + mw + lm) * HD;
    h8 qf[4];
    #pragma unroll
    for (int ks = 0; ks < 4; ++ks) qf[ks] = *(const h8*)&qT[qb + ks * 16 + hi * 8];

    const int sr = t >> 2;                  // staging row 0..63 (4 threads/row)
    const int scol = (t & 3) * 16;          // element offset within row (2 h8)
    const _Float16* ka = kT + (size_t)bh * N_TOK * HD + (size_t)(cs * 64 + sr) * HD + scol;
    const _Float16* va = vW + (size_t)bh * HD * N_TOK + (size_t)sr * N_TOK + cs * 64 + scol;

    float m_run = -1e30f, l_run = 0.f;
    f32x16 o_acc[2] = {};

    // prologue: stage first chunk into buffer 0
    {
        h8 pk0 = *(const h8*)&ka[0], pk1 = *(const h8*)&ka[8];
        h8 pv0 = *(const h8*)&va[0], pv1 = *(const h8*)&va[8];
        ka += 64 * HD; va += 64;
        *(h8*)&Ks[sr * 72 + scol] = pk0; *(h8*)&Ks[sr * 72 + scol + 8] = pk1;
        *(h8*)&Vs[sr * 72 + scol] = pv0; *(h8*)&Vs[sr * 72 + scol + 8] = pv1;
    }
    __syncthreads();

    int coff = 0;   // current-buffer element offset (scalar; toggles by KBUF)
    for (int ch = cs; ch < ce; ++ch) {
        const bool pf = (ch + 1 < ce);
        h8 pk0, pk1, pv0, pv1;
        if (pf) {   // issue next-chunk loads early; latency hides under compute
            pk0 = *(const h8*)&ka[0]; pk1 = *(const h8*)&ka[8];
            pv0 = *(const h8*)&va[0]; pv1 = *(const h8*)&va[8];
            ka += 64 * HD; va += 64;
        }

        // QK^T (swapped): A = K rows (keys), B = Q; D[key][query]; logits in log2 units
        f32x16 s0 = {}, s1 = {};
        __builtin_amdgcn_s_setprio(1);
        #pragma unroll
        for (int ks = 0; ks < 4; ++ks) {
            h8 a0 = *(const h8*)&Ks[coff + lm * 72 + ks * 16 + hi * 8];
            h8 a1 = *(const h8*)&Ks[coff + (32 + lm) * 72 + ks * 16 + hi * 8];
            s0 = __builtin_amdgcn_mfma_f32_32x32x16_f16(a0, qf[ks], s0, 0, 0, 0);
            s1 = __builtin_amdgcn_mfma_f32_32x32x16_f16(a1, qf[ks], s1, 0, 0, 0);
        }
        __builtin_amdgcn_s_setprio(0);

        // online softmax (exp2 space, raw v_exp_f32) with defer-max (THR=7)
        float cmax = -1e30f;
        #pragma unroll
        for (int r = 0; r < 16; ++r) cmax = fmaxf(cmax, fmaxf(s0[r], s1[r]));
        cmax = fmaxf(cmax, __shfl_xor(cmax, 32));
        if (!__all(cmax - m_run <= 7.f)) {
            float mnew = fmaxf(m_run, cmax);
            float alpha = fexp2(m_run - mnew);
            m_run = mnew;
            l_run *= alpha;
            #pragma unroll
            for (int r = 0; r < 16; ++r) { o_acc[0][r] *= alpha; o_acc[1][r] *= alpha; }
        }
        float p[2][16];
        float psum = 0.f;
        #pragma unroll
        for (int r = 0; r < 16; ++r) {
            p[0][r] = fexp2(s0[r] - m_run);
            p[1][r] = fexp2(s1[r] - m_run);
            psum += p[0][r] + p[1][r];
        }
        psum += __shfl_xor(psum, 32);
        l_run += psum;

        // P -> B-operand fragments in-register (cvt_pkrtz + permlane32_swap)
        h8 pfrag[4];
        #pragma unroll
        for (int kt = 0; kt < 2; ++kt) {
            #pragma unroll
            for (int half = 0; half < 2; ++half) {
                const int b0 = half * 8;
                unsigned w01 = pkh(p[kt][b0 + 0], p[kt][b0 + 1]);
                unsigned w23 = pkh(p[kt][b0 + 2], p[kt][b0 + 3]);
                unsigned w45 = pkh(p[kt][b0 + 4], p[kt][b0 + 5]);
                unsigned w67 = pkh(p[kt][b0 + 6], p[kt][b0 + 7]);
                plswap(w01, w45);
                plswap(w23, w67);
                u32x4 uu = {w01, w23, w45, w67};
                pfrag[kt * 2 + half] = __builtin_bit_cast(h8, uu);
            }
        }

        // PV: A = V rows (d), B = P; D[d][query]
        __builtin_amdgcn_s_setprio(1);
        #pragma unroll
        for (int ns = 0; ns < 4; ++ns) {
            h8 av0 = *(const h8*)&Vs[coff + lm * 72 + ns * 16 + hi * 8];
            h8 av1 = *(const h8*)&Vs[coff + (32 + lm) * 72 + ns * 16 + hi * 8];
            o_acc[0] = __builtin_amdgcn_mfma_f32_32x32x16_f16(av0, pfrag[ns], o_acc[0], 0, 0, 0);
            o_acc[1] = __builtin_amdgcn_mfma_f32_32x32x16_f16(av1, pfrag[ns], o_acc[1], 0, 0, 0);
        }
        __builtin_amdgcn_s_setprio(0);

        if (pf) {
            const int noff = coff ^ KBUF;
            // write to the OTHER buffer: no pre-write barrier needed
            *(h8*)&Ks[noff + sr * 72 + scol] = pk0; *(h8*)&Ks[noff + sr * 72 + scol + 8] = pk1;
            *(h8*)&Vs[noff + sr * 72 + scol] = pv0; *(h8*)&Vs[noff + sr * 72 + scol + 8] = pv1;
            __syncthreads();   // one barrier/chunk: nb complete AND all waves past cur
            coff = noff;
        }
    }

    // epilogue: store per-split normalized O (f16) + m,l (f32)
    float inv = 1.0f / l_run;
    _Float16* pO = (split == 0) ? wsbase
                                : wsbase + WS_PO13 + (size_t)(split - 1) * SPLIT_O;
    const size_t pob = (size_t)bh * HD * N_TOK + mw + lm;
    #pragma unroll
    for (int dt = 0; dt < 2; ++dt)
        #pragma unroll
        for (int r = 0; r < 16; ++r) {
            int d = dt * 32 + (r & 3) + 8 * (r >> 2) + 4 * hi;
            pO[pob + (size_t)d * N_TOK] = (_Float16)(o_acc[dt][r] * inv);
        }
    if (hi == 0) {
        pm[(split * 16 + bh) * N_TOK + mw + lm] = m_run;
        pl[(split * 16 + bh) * N_TOK + mw + lm] = l_run;
    }
}

// ---------- combine the four key-splits, 4 elements/thread (vectorized) ----------
__global__ __launch_bounds__(256) void k_comb(const _Float16* __restrict__ wsbase,
                                              const float* __restrict__ pm,
                                              const float* __restrict__ pl,
                                              float* __restrict__ out) {
    // 3,211,264 elements = 3136 blocks x 256 threads x 4
    int base = (blockIdx.x * 256 + threadIdx.x) * 4;
    int n = base % N_TOK;                 // N_TOK % 4 == 0: packs never straddle rows
    int bh = (base / N_TOK) >> 6;
    f32x4 num = {}, den = {};
    float mm[4];
    f32x4 mv[4], lv[4];
    #pragma unroll
    for (int s = 0; s < 4; ++s) {
        mv[s] = *(const f32x4*)&pm[(s * 16 + bh) * N_TOK + n];
        lv[s] = *(const f32x4*)&pl[(s * 16 + bh) * N_TOK + n];
    }
    #pragma unroll
    for (int j = 0; j < 4; ++j)
        mm[j] = fmaxf(fmaxf(mv[0][j], mv[1][j]), fmaxf(mv[2][j], mv[3][j]));
    #pragma unroll
    for (int s = 0; s < 4; ++s) {
        const _Float16* pO = (s == 0) ? wsbase
                                      : wsbase + WS_PO13 + (size_t)(s - 1) * SPLIT_O;
        h4 ov = *(const h4*)&pO[base];
        #pragma unroll
        for (int j = 0; j < 4; ++j) {
            float wg = fexp2(mv[s][j] - mm[j]) * lv[s][j];
            num[j] += (float)ov[j] * wg;
            den[j] += wg;
        }
    }
    f32x4 res;
    #pragma unroll
    for (int j = 0; j < 4; ++j) res[j] = num[j] / den[j];
    *(f32x4*)&out[base] = res;
}

extern "C" void kernel_launch(void* const* d_in, const int* in_sizes, int n_in,
                              void* d_out, int out_size, void* d_ws, size_t ws_size,
                              hipStream_t stream) {
    const float* x = (const float*)d_in[0];
    const float* wq = (const float*)d_in[1];
    float* out = (float*)d_out;
    _Float16* ws = (_Float16*)d_ws;

    _Float16* xh = ws + WS_XH;
    _Float16* wf = ws + WS_WF;
    _Float16* qT = ws + WS_QT;
    _Float16* kT = ws + WS_KT;
    _Float16* vW = ws + WS_VW;
    float* pm = (float*)(ws + WS_ML);
    float* pl = pm + ML_N;

    k_ds<<<dim3(49, 9, 2), 256, 0, stream>>>(x, wq, xh, wf);
    k_proj<<<dim3(25, 12, 2), 256, 0, stream>>>(wf, xh, qT, kT, vW);
    k_attn<<<dim3(25, 16, 4), 256, 0, stream>>>(qT, kT, vW, ws, pm, pl);
    k_comb<<<dim3(3136), 256, 0, stream>>>(ws, pm, pl, out);
}

// Round 26
// 125.999 us; speedup vs baseline: 1.0635x; 1.0105x over previous
//
#include <hip/hip_runtime.h>

#define N_TOK 3136   // 56*56
#define WOUT 56
#define CH 512
#define HD 64
#define LOG2E 1.44269504088896340736f
#define KBUF 4608    // 64*72 halves per K/V buffer

typedef _Float16 h4 __attribute__((ext_vector_type(4)));
typedef _Float16 h8 __attribute__((ext_vector_type(8)));
typedef float f32x4 __attribute__((ext_vector_type(4)));
typedef float f32x16 __attribute__((ext_vector_type(16)));
typedef unsigned u32x2 __attribute__((ext_vector_type(2)));
typedef unsigned u32x4 __attribute__((ext_vector_type(4)));

// ws offsets in f16 elements
#define WS_XH 0                 // x f16 (3211264), dead after k_proj -> pO split 0
#define WS_WF 3211264           // w f16 (786432)
#define WS_QT 3997696
#define WS_KT 7208960
#define WS_VW 10420224
#define WS_PO13 13631488        // pO splits 1..3 (3 x 3211264)
#define WS_ML 23265280          // f32 m/l arrays
#define SPLIT_O 3211264         // per-split partial-O element count (16*64*3136)
#define ML_N 200704             // 4*16*3136 per array

__device__ inline unsigned pkh(float a, float b) {
    return __builtin_bit_cast(unsigned, __builtin_amdgcn_cvt_pkrtz(a, b));
}
// raw v_exp_f32: 2^x, single instruction (avoid precise-libm exp2f)
__device__ inline float fexp2(float x) {
#if __has_builtin(__builtin_amdgcn_exp2f)
    return __builtin_amdgcn_exp2f(x);
#else
    float r;
    asm("v_exp_f32 %0, %1" : "=v"(r) : "v"(x));
    return r;
#endif
}
// swap: lanes>=32 of a  <->  lanes<32 of b
__device__ inline void plswap(unsigned& a, unsigned& b) {
#if __has_builtin(__builtin_amdgcn_permlane32_swap)
    u32x2 r = __builtin_amdgcn_permlane32_swap(a, b, false, false);
    a = r.x; b = r.y;
#else
    unsigned a2 = (unsigned)__shfl_xor((int)a, 32);
    unsigned b2 = (unsigned)__shfl_xor((int)b, 32);
    bool hi = (threadIdx.x & 63) >= 32;
    unsigned na = hi ? b2 : a;
    unsigned nb = hi ? b : a2;
    a = na; b = nb;
#endif
}

// ---------- downsample + transpose + f16; y==8 blocks convert w ----------
__global__ __launch_bounds__(256) void k_ds(const float* __restrict__ x,
                                            const float* __restrict__ w,
                                            _Float16* __restrict__ xh,
                                            _Float16* __restrict__ wf) {
    const int t = threadIdx.x;
    if (blockIdx.y == 8) {   // w fp32 -> f16 (1536*512 = 786432 elements)
        int base = (blockIdx.z * 49 + blockIdx.x) * 8192 + t;
        #pragma unroll 8
        for (int i = 0; i < 32; ++i) {
            int idx = base + i * 256;
            if (idx < 1536 * 512) wf[idx] = (_Float16)w[idx];
        }
        return;
    }
    __shared__ float tile[64 * 65];
    const int q = t >> 6, l = t & 63;
    const int n0 = blockIdx.x * 64, c0 = blockIdx.y * 64, b = blockIdx.z;
    #pragma unroll
    for (int r = 0; r < 16; ++r) {
        int c_l = q * 16 + r;
        int n = n0 + l;
        int hh = n / WOUT, ww = n - hh * WOUT;
        tile[c_l * 65 + l] =
            x[(((size_t)(b * CH + c0 + c_l)) * 112 + hh * 2) * 112 + ww * 2];
    }
    __syncthreads();
    #pragma unroll
    for (int r = 0; r < 16; ++r) {
        int n_l = q * 16 + r;
        xh[((size_t)b * N_TOK + n0 + n_l) * CH + c0 + l] = (_Float16)tile[l * 65 + n_l];
    }
}

// ---------- projection, 128x128 tile, BK=64; K pre-scaled by log2(e) ----------
__global__ __launch_bounds__(256) void k_proj(const _Float16* __restrict__ wf,
                                              const _Float16* __restrict__ xh,
                                              _Float16* __restrict__ qT,
                                              _Float16* __restrict__ kT,
                                              _Float16* __restrict__ vW) {
    __shared__ __align__(16) _Float16 Wt[128 * 72];
    __shared__ __align__(16) _Float16 Xt[128 * 72];
    const int t = threadIdx.x;
    const int mtn = blockIdx.x;                           // 0..24 token tiles
    const int n0 = (mtn == 24) ? (N_TOK - 128) : mtn * 128;  // benign overlap on last
    const int o0 = blockIdx.y * 128;
    const int b = blockIdx.z;
    const int w = t >> 6, L = t & 63, lm = L & 15, g = L >> 4;
    const int sr = t >> 1, sc = (t & 1) * 32;   // 128 rows x 2 col-chunks per thread

    f32x4 acc[2][8] = {};
    for (int kc = 0; kc < 8; ++kc) {
        const int c0 = kc * 64;
        const size_t wb = (size_t)(o0 + sr) * CH + c0 + sc;
        const size_t xb = ((size_t)b * N_TOK + n0 + sr) * CH + c0 + sc;
        h8 rw[4], rx[4];
        #pragma unroll
        for (int i = 0; i < 4; ++i) {
            rw[i] = *(const h8*)&wf[wb + i * 8];
            rx[i] = *(const h8*)&xh[xb + i * 8];
        }
        __syncthreads();   // previous iteration's reads done
        #pragma unroll
        for (int i = 0; i < 4; ++i) {
            *(h8*)&Wt[sr * 72 + sc + i * 8] = rw[i];
            *(h8*)&Xt[sr * 72 + sc + i * 8] = rx[i];
        }
        __syncthreads();
        #pragma unroll
        for (int kk2 = 0; kk2 < 2; ++kk2) {
            const int kb = kk2 * 32 + g * 8;
            h8 a0 = *(h8*)&Wt[(w * 32 + lm) * 72 + kb];
            h8 a1 = *(h8*)&Wt[(w * 32 + 16 + lm) * 72 + kb];
            #pragma unroll
            for (int nt = 0; nt < 8; ++nt) {
                h8 bf = *(h8*)&Xt[(nt * 16 + lm) * 72 + kb];
                acc[0][nt] = __builtin_amdgcn_mfma_f32_16x16x32_f16(a0, bf, acc[0][nt], 0, 0, 0);
                acc[1][nt] = __builtin_amdgcn_mfma_f32_16x16x32_f16(a1, bf, acc[1][nt], 0, 0, 0);
            }
        }
    }
    #pragma unroll
    for (int ot = 0; ot < 2; ++ot) {
        int obase = o0 + w * 32 + ot * 16;
        int h = obase / 192;
        int typ = (obase / 64) % 3;
        int dbase = obase & 63;
        #pragma unroll
        for (int nt = 0; nt < 8; ++nt) {
            int n = n0 + nt * 16 + lm;
            f32x4 a = acc[ot][nt];
            if (typ == 2) {
                #pragma unroll
                for (int j = 0; j < 4; ++j)
                    vW[((size_t)(b * 8 + h) * HD + dbase + g * 4 + j) * N_TOK + n] = (_Float16)a[j];
            } else if (typ == 1) {
                h4 hv = {(_Float16)(a[0] * LOG2E), (_Float16)(a[1] * LOG2E),
                         (_Float16)(a[2] * LOG2E), (_Float16)(a[3] * LOG2E)};
                *(h4*)&kT[((size_t)(b * 8 + h) * N_TOK + n) * HD + dbase + g * 4] = hv;
            } else {
                h4 hv = {(_Float16)a[0], (_Float16)a[1], (_Float16)a[2], (_Float16)a[3]};
                *(h4*)&qT[((size_t)(b * 8 + h) * N_TOK + n) * HD + dbase + g * 4] = hv;
            }
        }
    }
}

// ---------- flash attention: S=4, dbuf, PV moved past the barrier (MFMA back-to-back) ----------
__global__ __launch_bounds__(256, 2) void k_attn(const _Float16* __restrict__ qT,
                                                 const _Float16* __restrict__ kT,
                                                 const _Float16* __restrict__ vW,
                                                 _Float16* __restrict__ wsbase,
                                                 float* __restrict__ pm,
                                                 float* __restrict__ pl) {
    __shared__ __align__(16) _Float16 Ks[2 * KBUF];   // [buf][n][d], pitch 72
    __shared__ __align__(16) _Float16 Vs[2 * KBUF];   // [buf][d][n], pitch 72

    const int t = threadIdx.x;
    const int w = t >> 6, L = t & 63, lm = L & 31, hi = L >> 5;

    // bijective chunked XCD swizzle: 1600 blocks = 8 XCDs x 200
    const int lin = blockIdx.x + 25 * blockIdx.y + 400 * blockIdx.z;
    const int nl = (lin & 7) * 200 + (lin >> 3);
    const int combo = nl / 25;              // 0..63 : (split, bh)
    const int mt = nl - combo * 25;
    const int bh = combo & 15;
    const int split = combo >> 4;
    // QBLK=128; clamp last block (benign overlap)
    const int qbase = (mt == 24) ? (N_TOK - 128) : mt * 128;
    const int mw = qbase + w * 32;

    const int cs = split * 12 + (split > 0 ? 1 : 0);   // {0,13,25,37}
    const int ce = cs + (split == 0 ? 13 : 12);

    // hoist Q (B-operand): lane: query col = lm, k-slice = hi*8
    const size_t qb = ((size_t)bh * N_TOK + mw + lm) * HD;
    h8 qf[4];
    #pragma unroll
    for (int ks = 0; ks < 4; ++ks) qf[ks] = *(const h8*)&qT[qb + ks * 16 + hi * 8];

    const int sr = t >> 2;                  // staging row 0..63 (4 threads/row)
    const int scol = (t & 3) * 16;          // element offset within row (2 h8)
    const _Float16* ka = kT + (size_t)bh * N_TOK * HD + (size_t)(cs * 64 + sr) * HD + scol;
    const _Float16* va = vW + (size_t)bh * HD * N_TOK + (size_t)sr * N_TOK + cs * 64 + scol;

    float m_run = -1e30f, l_run = 0.f;
    f32x16 o_acc[2] = {};

    // prologue: stage first chunk into buffer 0
    {
        h8 pk0 = *(const h8*)&ka[0], pk1 = *(const h8*)&ka[8];
        h8 pv0 = *(const h8*)&va[0], pv1 = *(const h8*)&va[8];
        ka += 64 * HD; va += 64;
        *(h8*)&Ks[sr * 72 + scol] = pk0; *(h8*)&Ks[sr * 72 + scol + 8] = pk1;
        *(h8*)&Vs[sr * 72 + scol] = pv0; *(h8*)&Vs[sr * 72 + scol + 8] = pv1;
    }
    __syncthreads();

    int coff = 0;   // current-buffer element offset (scalar; toggles by KBUF)
    for (int ch = cs; ch < ce; ++ch) {
        const bool pf = (ch + 1 < ce);
        h8 pk0, pk1, pv0, pv1;
        if (pf) {   // issue next-chunk loads early; latency hides under QK+softmax
            pk0 = *(const h8*)&ka[0]; pk1 = *(const h8*)&ka[8];
            pv0 = *(const h8*)&va[0]; pv1 = *(const h8*)&va[8];
            ka += 64 * HD; va += 64;
        }

        // QK^T (swapped): A = K rows (keys), B = Q; D[key][query]; logits in log2 units
        f32x16 s0 = {}, s1 = {};
        __builtin_amdgcn_s_setprio(1);
        #pragma unroll
        for (int ks = 0; ks < 4; ++ks) {
            h8 a0 = *(const h8*)&Ks[coff + lm * 72 + ks * 16 + hi * 8];
            h8 a1 = *(const h8*)&Ks[coff + (32 + lm) * 72 + ks * 16 + hi * 8];
            s0 = __builtin_amdgcn_mfma_f32_32x32x16_f16(a0, qf[ks], s0, 0, 0, 0);
            s1 = __builtin_amdgcn_mfma_f32_32x32x16_f16(a1, qf[ks], s1, 0, 0, 0);
        }
        __builtin_amdgcn_s_setprio(0);

        // online softmax (exp2 space, raw v_exp_f32) with defer-max (THR=7)
        float cmax = -1e30f;
        #pragma unroll
        for (int r = 0; r < 16; ++r) cmax = fmaxf(cmax, fmaxf(s0[r], s1[r]));
        cmax = fmaxf(cmax, __shfl_xor(cmax, 32));
        if (!__all(cmax - m_run <= 7.f)) {
            float mnew = fmaxf(m_run, cmax);
            float alpha = fexp2(m_run - mnew);
            m_run = mnew;
            l_run *= alpha;
            #pragma unroll
            for (int r = 0; r < 16; ++r) { o_acc[0][r] *= alpha; o_acc[1][r] *= alpha; }
        }
        float p[2][16];
        float psum = 0.f;
        #pragma unroll
        for (int r = 0; r < 16; ++r) {
            p[0][r] = fexp2(s0[r] - m_run);
            p[1][r] = fexp2(s1[r] - m_run);
            psum += p[0][r] + p[1][r];
        }
        psum += __shfl_xor(psum, 32);
        l_run += psum;

        // P -> B-operand fragments in-register (cvt_pkrtz + permlane32_swap)
        h8 pfrag[4];
        #pragma unroll
        for (int kt = 0; kt < 2; ++kt) {
            #pragma unroll
            for (int half = 0; half < 2; ++half) {
                const int b0 = half * 8;
                unsigned w01 = pkh(p[kt][b0 + 0], p[kt][b0 + 1]);
                unsigned w23 = pkh(p[kt][b0 + 2], p[kt][b0 + 3]);
                unsigned w45 = pkh(p[kt][b0 + 4], p[kt][b0 + 5]);
                unsigned w67 = pkh(p[kt][b0 + 6], p[kt][b0 + 7]);
                plswap(w01, w45);
                plswap(w23, w67);
                u32x4 uu = {w01, w23, w45, w67};
                pfrag[kt * 2 + half] = __builtin_bit_cast(h8, uu);
            }
        }

        // stage next chunk + barrier BEFORE PV: cur buffer stays valid (dbuf),
        // and PV(ch) flows straight into QK(ch+1) after the barrier (two
        // independent MFMA streams back-to-back across the chunk boundary)
        if (pf) {
            const int noff = coff ^ KBUF;
            *(h8*)&Ks[noff + sr * 72 + scol] = pk0; *(h8*)&Ks[noff + sr * 72 + scol + 8] = pk1;
            *(h8*)&Vs[noff + sr * 72 + scol] = pv0; *(h8*)&Vs[noff + sr * 72 + scol + 8] = pv1;
            __syncthreads();
        }

        // PV: A = V rows (d), B = P; D[d][query]  (reads OLD buffer coff)
        __builtin_amdgcn_s_setprio(1);
        #pragma unroll
        for (int ns = 0; ns < 4; ++ns) {
            h8 av0 = *(const h8*)&Vs[coff + lm * 72 + ns * 16 + hi * 8];
            h8 av1 = *(const h8*)&Vs[coff + (32 + lm) * 72 + ns * 16 + hi * 8];
            o_acc[0] = __builtin_amdgcn_mfma_f32_32x32x16_f16(av0, pfrag[ns], o_acc[0], 0, 0, 0);
            o_acc[1] = __builtin_amdgcn_mfma_f32_32x32x16_f16(av1, pfrag[ns], o_acc[1], 0, 0, 0);
        }
        __builtin_amdgcn_s_setprio(0);

        if (pf) coff ^= KBUF;
    }

    // epilogue: store per-split normalized O (f16) + m,l (f32)
    float inv = 1.0f / l_run;
    _Float16* pO = (split == 0) ? wsbase
                                : wsbase + WS_PO13 + (size_t)(split - 1) * SPLIT_O;
    const size_t pob = (size_t)bh * HD * N_TOK + mw + lm;
    #pragma unroll
    for (int dt = 0; dt < 2; ++dt)
        #pragma unroll
        for (int r = 0; r < 16; ++r) {
            int d = dt * 32 + (r & 3) + 8 * (r >> 2) + 4 * hi;
            pO[pob + (size_t)d * N_TOK] = (_Float16)(o_acc[dt][r] * inv);
        }
    if (hi == 0) {
        pm[(split * 16 + bh) * N_TOK + mw + lm] = m_run;
        pl[(split * 16 + bh) * N_TOK + mw + lm] = l_run;
    }
}

// ---------- combine the four key-splits, 4 elements/thread (vectorized) ----------
__global__ __launch_bounds__(256) void k_comb(const _Float16* __restrict__ wsbase,
                                              const float* __restrict__ pm,
                                              const float* __restrict__ pl,
                                              float* __restrict__ out) {
    // 3,211,264 elements = 3136 blocks x 256 threads x 4
    int base = (blockIdx.x * 256 + threadIdx.x) * 4;
    int n = base % N_TOK;                 // N_TOK % 4 == 0: packs never straddle rows
    int bh = (base / N_TOK) >> 6;
    f32x4 num = {}, den = {};
    float mm[4];
    f32x4 mv[4], lv[4];
    #pragma unroll
    for (int s = 0; s < 4; ++s) {
        mv[s] = *(const f32x4*)&pm[(s * 16 + bh) * N_TOK + n];
        lv[s] = *(const f32x4*)&pl[(s * 16 + bh) * N_TOK + n];
    }
    #pragma unroll
    for (int j = 0; j < 4; ++j)
        mm[j] = fmaxf(fmaxf(mv[0][j], mv[1][j]), fmaxf(mv[2][j], mv[3][j]));
    #pragma unroll
    for (int s = 0; s < 4; ++s) {
        const _Float16* pO = (s == 0) ? wsbase
                                      : wsbase + WS_PO13 + (size_t)(s - 1) * SPLIT_O;
        h4 ov = *(const h4*)&pO[base];
        #pragma unroll
        for (int j = 0; j < 4; ++j) {
            float wg = fexp2(mv[s][j] - mm[j]) * lv[s][j];
            num[j] += (float)ov[j] * wg;
            den[j] += wg;
        }
    }
    f32x4 res;
    #pragma unroll
    for (int j = 0; j < 4; ++j) res[j] = num[j] / den[j];
    *(f32x4*)&out[base] = res;
}

extern "C" void kernel_launch(void* const* d_in, const int* in_sizes, int n_in,
                              void* d_out, int out_size, void* d_ws, size_t ws_size,
                              hipStream_t stream) {
    const float* x = (const float*)d_in[0];
    const float* wq = (const float*)d_in[1];
    float* out = (float*)d_out;
    _Float16* ws = (_Float16*)d_ws;

    _Float16* xh = ws + WS_XH;
    _Float16* wf = ws + WS_WF;
    _Float16* qT = ws + WS_QT;
    _Float16* kT = ws + WS_KT;
    _Float16* vW = ws + WS_VW;
    float* pm = (float*)(ws + WS_ML);
    float* pl = pm + ML_N;

    k_ds<<<dim3(49, 9, 2), 256, 0, stream>>>(x, wq, xh, wf);
    k_proj<<<dim3(25, 12, 2), 256, 0, stream>>>(wf, xh, qT, kT, vW);
    k_attn<<<dim3(25, 16, 4), 256, 0, stream>>>(qT, kT, vW, ws, pm, pl);
    k_comb<<<dim3(3136), 256, 0, stream>>>(ws, pm, pl, out);
}